// Round 12
// baseline (213.485 us; speedup 1.0000x reference)
//
#include <hip/hip_runtime.h>
#include <math.h>

// Problem constants
#define CCH 64
#define HH  128
#define WW  128
#define NB  4
#define NPIX (NB*HH*WW)   // 65536
#define NWG  (NPIX/64)    // 1024 blocks for the pixel kernels

// XCD-aware block swizzle (T1): each XCD gets a contiguous 64-row slice.
__device__ __forceinline__ int swz_block(int bid) {
    return (bid & 7) * (NWG >> 3) + (bid >> 3);
}

// ---------------------------------------------------------------------------
// Prep: transpose conv weights for wave-uniform contiguous rows.
//   offT[(ic*9+kk)*28 + o]  = off_w[o*576 + ic*9 + kk]   (o<27, pad->0)
//   dcnT[(k*64+ic)*64 + o]  = dcn_w[o*576 + ic*9 + k]
// ---------------------------------------------------------------------------
__global__ __launch_bounds__(256) void prep_kernel(
    const float* __restrict__ off_w, const float* __restrict__ dcn_w,
    float* __restrict__ offT, float* __restrict__ dcnT)
{
    int idx = blockIdx.x * 256 + threadIdx.x;
    if (idx < 576 * 28) {
        int rc = idx / 28;       // ic*9+kk
        int o  = idx % 28;
        offT[rc * 28 + o] = (o < 27) ? off_w[o * 576 + rc] : 0.0f;
    }
    if (idx < 36864) {
        int o    = idx & 63;
        int rest = idx >> 6;
        int ic   = rest & 63;
        int k    = rest >> 6;
        dcnT[(k * 64 + ic) * 64 + o] = dcn_w[o * 576 + ic * 9 + k];
    }
}

// ---------------------------------------------------------------------------
// Kernel 1: fused 4-layer MLP -> feat2 (NHWC, for dcn gather) AND
// featN (NCHW, aliased into d_out -- dead until dcn's final write).
// ---------------------------------------------------------------------------
__global__ __launch_bounds__(256) void mlp_kernel(
    const float* __restrict__ ev, const float* __restrict__ im,
    const float* __restrict__ w0, const float* __restrict__ b0,
    const float* __restrict__ w1, const float* __restrict__ b1,
    const float* __restrict__ w2, const float* __restrict__ b2,
    const float* __restrict__ w3, const float* __restrict__ b3,
    float* __restrict__ feat2, float* __restrict__ featN)
{
    __shared__ float xA[64 * 65];   // [ch][px], padded
    __shared__ float xB[64 * 65];
    int tid  = threadIdx.x;
    int cg   = __builtin_amdgcn_readfirstlane(tid >> 6);
    int lane = tid & 63;
    int sw   = swz_block(blockIdx.x);
    int p = sw * 64 + lane;
    int b = p >> 14;
    int q = p & 16383;
    int h = q >> 7;
    int w = q & 127;
    int c0 = cg * 16;

    float acc[16];
#pragma unroll
    for (int j = 0; j < 16; ++j) acc[j] = b0[c0 + j];

    const float* evb = ev + ((b * 64) * 64 + (h >> 1)) * 64 + (w >> 1);
    for (int i = 0; i < 64; ++i) {
        float v = evb[i * 4096];
        const float* wr = w0 + i * 64 + c0;
#pragma unroll
        for (int j = 0; j < 16; ++j) acc[j] = fmaf(v, wr[j], acc[j]);
    }
    const float* imb = im + ((b * 64) * 128 + h) * 128 + w;
    for (int i = 0; i < 64; ++i) {
        float v = imb[i * 16384];
        const float* wr = w0 + (64 + i) * 64 + c0;
#pragma unroll
        for (int j = 0; j < 16; ++j) acc[j] = fmaf(v, wr[j], acc[j]);
    }
    {
        float rely = (h & 1) ? 0.5f : -0.5f;
        float relx = (w & 1) ? 0.5f : -0.5f;
        const float* wr = w0 + 128 * 64 + c0;
#pragma unroll
        for (int j = 0; j < 16; ++j) acc[j] = fmaf(rely, wr[j], acc[j]);
#pragma unroll
        for (int j = 0; j < 16; ++j) acc[j] = fmaf(relx, wr[64 + j], acc[j]);
#pragma unroll
        for (int j = 0; j < 16; ++j) acc[j] += wr[128 + j] + wr[192 + j];
    }
#pragma unroll
    for (int j = 0; j < 16; ++j) xA[(c0 + j) * 65 + lane] = fmaxf(acc[j], 0.0f);
    __syncthreads();

#pragma unroll
    for (int j = 0; j < 16; ++j) acc[j] = b1[c0 + j];
    for (int i = 0; i < 64; ++i) {
        float v = xA[i * 65 + lane];
        const float* wr = w1 + i * 64 + c0;
#pragma unroll
        for (int j = 0; j < 16; ++j) acc[j] = fmaf(v, wr[j], acc[j]);
    }
#pragma unroll
    for (int j = 0; j < 16; ++j) xB[(c0 + j) * 65 + lane] = fmaxf(acc[j], 0.0f);
    __syncthreads();

#pragma unroll
    for (int j = 0; j < 16; ++j) acc[j] = b2[c0 + j];
    for (int i = 0; i < 64; ++i) {
        float v = xB[i * 65 + lane];
        const float* wr = w2 + i * 64 + c0;
#pragma unroll
        for (int j = 0; j < 16; ++j) acc[j] = fmaf(v, wr[j], acc[j]);
    }
#pragma unroll
    for (int j = 0; j < 16; ++j) xA[(c0 + j) * 65 + lane] = fmaxf(acc[j], 0.0f);
    __syncthreads();

#pragma unroll
    for (int j = 0; j < 16; ++j) acc[j] = b3[c0 + j];
    for (int i = 0; i < 64; ++i) {
        float v = xA[i * 65 + lane];
        const float* wr = w3 + i * 64 + c0;
#pragma unroll
        for (int j = 0; j < 16; ++j) acc[j] = fmaf(v, wr[j], acc[j]);
    }

    // NCHW store (coalesced: lanes = consecutive px)
    float* fbN = featN + (b * 64 + c0) * 16384 + q;
#pragma unroll
    for (int j = 0; j < 16; ++j) fbN[j * 16384] = acc[j];

    // NHWC store via padded-LDS transpose (coalesced float4)
#pragma unroll
    for (int j = 0; j < 16; ++j) xB[(c0 + j) * 65 + lane] = acc[j];
    __syncthreads();
    {
        int q0 = (sw * 64) & 16383;
        float* fb = feat2 + ((size_t)b * 16384 + q0) * 64;
        int ch0 = (tid & 15) * 4;
#pragma unroll
        for (int r = 0; r < 4; ++r) {
            int px = (tid >> 4) + r * 16;
            float4 v = make_float4(xB[(ch0 + 0) * 65 + px],
                                   xB[(ch0 + 1) * 65 + px],
                                   xB[(ch0 + 2) * 65 + px],
                                   xB[(ch0 + 3) * 65 + px]);
            ((float4*)fb)[tid + r * 256] = v;
        }
    }
}

// ---------------------------------------------------------------------------
// Kernel 2: 3x3 offset conv -> raw 27-ch oo.  NCHW reads (featN in d_out).
// ---------------------------------------------------------------------------
__global__ __launch_bounds__(256) void off_kernel(
    const float* __restrict__ featN, const float* __restrict__ offT,
    const float* __restrict__ off_b,
    float* __restrict__ oo)
{
    __shared__ float po[4 * 27 * 64];   // [wave][o][px]
    int tid  = threadIdx.x;
    int wv   = __builtin_amdgcn_readfirstlane(tid >> 6);
    int lane = tid & 63;
    int p = swz_block(blockIdx.x) * 64 + lane;
    int b = p >> 14;
    int q = p & 16383;
    int h = q >> 7;
    int w = q & 127;
    int c0 = wv * 16;

    float acc[27];
#pragma unroll
    for (int o = 0; o < 27; ++o) acc[o] = 0.0f;

    const float* fb = featN + (b * 64 + c0) * 16384;
    for (int i = 0; i < 16; ++i) {
        const float* f = fb + i * 16384;
        float v[9];
#pragma unroll
        for (int ky = 0; ky < 3; ++ky)
#pragma unroll
            for (int kx = 0; kx < 3; ++kx) {
                int y = h + ky - 1, x = w + kx - 1;
                bool ok = (y >= 0) && (y < 128) && (x >= 0) && (x < 128);
                v[ky * 3 + kx] = ok ? f[y * 128 + x] : 0.0f;
            }
#pragma unroll
        for (int kk = 0; kk < 9; ++kk) {
            const float* wr = offT + ((c0 + i) * 9 + kk) * 28;
#pragma unroll
            for (int o = 0; o < 27; ++o) acc[o] = fmaf(v[kk], wr[o], acc[o]);
        }
    }

#pragma unroll
    for (int o = 0; o < 27; ++o) po[(wv * 27 + o) * 64 + lane] = acc[o];
    __syncthreads();

#pragma unroll
    for (int j = 0; j < 7; ++j) {
        int o = wv + 4 * j;
        if (o < 27) {
            float s = off_b[o]
                    + po[o * 64 + lane] + po[(27 + o) * 64 + lane]
                    + po[(54 + o) * 64 + lane] + po[(81 + o) * 64 + lane];
            oo[((b * 27 + o) << 14) + q] = s;
        }
    }
}

// ---------------------------------------------------------------------------
// Kernel 3: transform + deformable sampling + einsum + bias.
// PARTIAL-SUM RESTRUCTURE: wave wv keeps its 16-ic samples in REGISTERS and
// accumulates partials for ALL 64 outputs (acc[64]); no barriers / no LDS in
// the k-loop. One staged LDS reduce (4 x 16 outputs, 16 KB) at the end.
// ---------------------------------------------------------------------------
__device__ __forceinline__ void dcn_transform_r(
    float oy, float ox, float mlraw, int k, int h, int w,
    float& W00, float& W01, float& W10, float& W11,
    int& i00, int& i01, int& i10, int& i11)
{
    float ml = 1.0f / (1.0f + expf(-mlraw));
    float py = (float)(h + k / 3 - 1) + oy;
    float px = (float)(w + k % 3 - 1) + ox;

    float y0f = floorf(py), x0f = floorf(px);
    float ly = py - y0f, lx = px - x0f;
    int y0 = (int)y0f, x0 = (int)x0f;

    bool vy0 = (y0f >= 0.0f)        && (y0f <= 127.0f);
    bool vy1 = (y0f + 1.0f >= 0.0f) && (y0f + 1.0f <= 127.0f);
    bool vx0 = (x0f >= 0.0f)        && (x0f <= 127.0f);
    bool vx1 = (x0f + 1.0f >= 0.0f) && (x0f + 1.0f <= 127.0f);

    int yc0 = min(max(y0, 0), 127),     yc1 = min(max(y0 + 1, 0), 127);
    int xc0 = min(max(x0, 0), 127),     xc1 = min(max(x0 + 1, 0), 127);

    W00 = (1.0f - ly) * (1.0f - lx) * ml * ((vy0 && vx0) ? 1.0f : 0.0f);
    W01 = (1.0f - ly) * lx          * ml * ((vy0 && vx1) ? 1.0f : 0.0f);
    W10 = ly * (1.0f - lx)          * ml * ((vy1 && vx0) ? 1.0f : 0.0f);
    W11 = ly * lx                   * ml * ((vy1 && vx1) ? 1.0f : 0.0f);

    i00 = yc0 * 128 + xc0; i01 = yc0 * 128 + xc1;
    i10 = yc1 * 128 + xc0; i11 = yc1 * 128 + xc1;
}

__global__ __launch_bounds__(256) void dcn_kernel(
    const float* __restrict__ feat2,
    const float* __restrict__ oo,
    const float* __restrict__ dcnT, const float* __restrict__ dcn_b,
    float* __restrict__ out)
{
    __shared__ float po[4 * 16 * 64];   // 16 KB staged reduce buffer
    int tid  = threadIdx.x;
    int wv   = __builtin_amdgcn_readfirstlane(tid >> 6);
    int lane = tid & 63;
    int p = swz_block(blockIdx.x) * 64 + lane;
    int b = p >> 14;
    int q = p & 16383;
    int h = q >> 7;
    int w = q & 127;
    int c0 = wv * 16;

    float acc[64];
#pragma unroll
    for (int o = 0; o < 64; ++o) acc[o] = 0.0f;

    const float* fb2 = feat2 + (size_t)(b * 16384) * 64 + c0;  // wave's slice
    const float* oob = oo + ((b * 27) << 14) + q;

    // prefetch oo for k=0
    float oyN = oob[0];
    float oxN = oob[1 << 14];
    float omN = oob[18 << 14];

    for (int k = 0; k < 9; ++k) {
        float W00, W01, W10, W11; int i00, i01, i10, i11;
        dcn_transform_r(oyN, oxN, omN, k, h, w, W00, W01, W10, W11,
                        i00, i01, i10, i11);
        if (k < 8) {   // prefetch next k's oo (hides under this k's work)
            oyN = oob[(2 * (k + 1)) << 14];
            oxN = oob[(2 * (k + 1) + 1) << 14];
            omN = oob[(18 + (k + 1)) << 14];
        }

        // corner-by-corner blend into s[16] (caps live VGPRs)
        float s[16];
        {
            const float4* P = (const float4*)(fb2 + i00 * 64);
            float4 v0 = P[0], v1 = P[1], v2 = P[2], v3 = P[3];
            s[0]=W00*v0.x; s[1]=W00*v0.y; s[2]=W00*v0.z; s[3]=W00*v0.w;
            s[4]=W00*v1.x; s[5]=W00*v1.y; s[6]=W00*v1.z; s[7]=W00*v1.w;
            s[8]=W00*v2.x; s[9]=W00*v2.y; s[10]=W00*v2.z; s[11]=W00*v2.w;
            s[12]=W00*v3.x; s[13]=W00*v3.y; s[14]=W00*v3.z; s[15]=W00*v3.w;
        }
        {
            const float4* P = (const float4*)(fb2 + i01 * 64);
            float4 v0 = P[0], v1 = P[1], v2 = P[2], v3 = P[3];
            s[0]=fmaf(W01,v0.x,s[0]); s[1]=fmaf(W01,v0.y,s[1]); s[2]=fmaf(W01,v0.z,s[2]); s[3]=fmaf(W01,v0.w,s[3]);
            s[4]=fmaf(W01,v1.x,s[4]); s[5]=fmaf(W01,v1.y,s[5]); s[6]=fmaf(W01,v1.z,s[6]); s[7]=fmaf(W01,v1.w,s[7]);
            s[8]=fmaf(W01,v2.x,s[8]); s[9]=fmaf(W01,v2.y,s[9]); s[10]=fmaf(W01,v2.z,s[10]); s[11]=fmaf(W01,v2.w,s[11]);
            s[12]=fmaf(W01,v3.x,s[12]); s[13]=fmaf(W01,v3.y,s[13]); s[14]=fmaf(W01,v3.z,s[14]); s[15]=fmaf(W01,v3.w,s[15]);
        }
        {
            const float4* P = (const float4*)(fb2 + i10 * 64);
            float4 v0 = P[0], v1 = P[1], v2 = P[2], v3 = P[3];
            s[0]=fmaf(W10,v0.x,s[0]); s[1]=fmaf(W10,v0.y,s[1]); s[2]=fmaf(W10,v0.z,s[2]); s[3]=fmaf(W10,v0.w,s[3]);
            s[4]=fmaf(W10,v1.x,s[4]); s[5]=fmaf(W10,v1.y,s[5]); s[6]=fmaf(W10,v1.z,s[6]); s[7]=fmaf(W10,v1.w,s[7]);
            s[8]=fmaf(W10,v2.x,s[8]); s[9]=fmaf(W10,v2.y,s[9]); s[10]=fmaf(W10,v2.z,s[10]); s[11]=fmaf(W10,v2.w,s[11]);
            s[12]=fmaf(W10,v3.x,s[12]); s[13]=fmaf(W10,v3.y,s[13]); s[14]=fmaf(W10,v3.z,s[14]); s[15]=fmaf(W10,v3.w,s[15]);
        }
        {
            const float4* P = (const float4*)(fb2 + i11 * 64);
            float4 v0 = P[0], v1 = P[1], v2 = P[2], v3 = P[3];
            s[0]=fmaf(W11,v0.x,s[0]); s[1]=fmaf(W11,v0.y,s[1]); s[2]=fmaf(W11,v0.z,s[2]); s[3]=fmaf(W11,v0.w,s[3]);
            s[4]=fmaf(W11,v1.x,s[4]); s[5]=fmaf(W11,v1.y,s[5]); s[6]=fmaf(W11,v1.z,s[6]); s[7]=fmaf(W11,v1.w,s[7]);
            s[8]=fmaf(W11,v2.x,s[8]); s[9]=fmaf(W11,v2.y,s[9]); s[10]=fmaf(W11,v2.z,s[10]); s[11]=fmaf(W11,v2.w,s[11]);
            s[12]=fmaf(W11,v3.x,s[12]); s[13]=fmaf(W11,v3.y,s[13]); s[14]=fmaf(W11,v3.z,s[14]); s[15]=fmaf(W11,v3.w,s[15]);
        }

        // partial einsum: this wave's 16 ic into ALL 64 outputs (s_load weights)
        const float* wk = dcnT + (size_t)k * 4096 + c0 * 64;
#pragma unroll
        for (int i = 0; i < 16; ++i) {
            const float* wr = wk + i * 64;
#pragma unroll
            for (int o = 0; o < 64; ++o) acc[o] = fmaf(s[i], wr[o], acc[o]);
        }
    }

    // staged cross-wave reduce: 4 stages x 16 outputs (16 KB LDS)
#pragma unroll
    for (int g = 0; g < 4; ++g) {
        if (g) __syncthreads();
#pragma unroll
        for (int j = 0; j < 16; ++j)
            po[(wv * 16 + j) * 64 + lane] = acc[g * 16 + j];
        __syncthreads();
#pragma unroll
        for (int j = 0; j < 4; ++j) {
            int oj = wv * 4 + j;           // output within stage, per wave
            int o  = g * 16 + oj;
            float sum = dcn_b[o]
                      + po[(0 * 16 + oj) * 64 + lane]
                      + po[(1 * 16 + oj) * 64 + lane]
                      + po[(2 * 16 + oj) * 64 + lane]
                      + po[(3 * 16 + oj) * 64 + lane];
            out[(b * 64 + o) * 16384 + q] = sum;
        }
    }
}

// ---------------------------------------------------------------------------
extern "C" void kernel_launch(void* const* d_in, const int* in_sizes, int n_in,
                              void* d_out, int out_size, void* d_ws, size_t ws_size,
                              hipStream_t stream)
{
    const float* ev    = (const float*)d_in[0];
    const float* im    = (const float*)d_in[1];
    const float* w0    = (const float*)d_in[2];
    const float* b0    = (const float*)d_in[3];
    const float* w1    = (const float*)d_in[4];
    const float* b1    = (const float*)d_in[5];
    const float* w2    = (const float*)d_in[6];
    const float* b2    = (const float*)d_in[7];
    const float* w3    = (const float*)d_in[8];
    const float* b3    = (const float*)d_in[9];
    const float* off_w = (const float*)d_in[10];
    const float* off_b = (const float*)d_in[11];
    const float* dcn_w = (const float*)d_in[12];
    const float* dcn_b = (const float*)d_in[13];
    float* out = (float*)d_out;

    char* ws = (char*)d_ws;
    float* feat2 = (float*)(ws);                       // 16,777,216 B (NHWC)
    float* oo    = (float*)(ws + 16777216);            //  7,077,888 B
    float* offT  = (float*)(ws + 23855104);            //     64,512 B
    float* dcnT  = (float*)(ws + 23920640);            //    147,456 B
    float* featN = out;   // NCHW copy aliased into d_out (dead before dcn's write)

    prep_kernel<<<144, 256, 0, stream>>>(off_w, dcn_w, offT, dcnT);
    mlp_kernel<<<NWG, 256, 0, stream>>>(ev, im, w0, b0, w1, b1, w2, b2,
                                        w3, b3, feat2, featN);
    off_kernel<<<NWG, 256, 0, stream>>>(featN, offT, off_b, oo);
    dcn_kernel<<<NWG, 256, 0, stream>>>(feat2, oo, dcnT, dcn_b, out);
}